// Round 9
// baseline (610.524 us; speedup 1.0000x reference)
//
#include <hip/hip_runtime.h>

#define NN 100000
#define EE 1600000
#define C 256
#define OUTC 10
#define NG 64

#define BSH 8              // bucket = node >> 8 (256-node buckets, scan granularity)
#define NBK 391            // ceil(NN/256)

// vectorized edge passes: 1 int4 (4 edges) per thread
#define E4 (EE / 4)                 // 400000 int4 slots
#define EBLK ((E4 + 255) / 256)     // 1563 blocks

// agg_pool decomposition: 4 waves/block, each wave owns NODES_PER_GROUP nodes
#define NODES_PER_GROUP 8
#define NODES_PER_BLOCK 32      // 100000 = 32 * 3125 exactly
#define AGG_BLOCKS 3125
#define AGG_Q 782               // quarter split: 782,782,782,779

#define PRE_CNT_BLKS 391        // count blocks
#define PRE_W1_BLKS 256         // w1pack blocks

typedef __bf16 bf16x8 __attribute__((ext_vector_type(8)));
typedef float f32x4 __attribute__((ext_vector_type(4)));
typedef float f32x2 __attribute__((ext_vector_type(2)));

// channel permutation: PHYSICAL byte position p in a g row holds LOGICAL
// channel c = ((p&15)<<4) | (p>>4)  (transpose involution).
__device__ __forceinline__ int chan_logical(int p) {
    return ((p & 15) << 4) | (p >> 4);
}

// ---------------- bf16 helpers (RNE) ----------------
__device__ __forceinline__ ushort f2bf(float f) {
    unsigned u = __float_as_uint(f);
    return (ushort)((u + 0x7fffu + ((u >> 16) & 1u)) >> 16);
}
__device__ __forceinline__ bf16x8 as_bf16x8(uint4 v) {
    union { uint4 u; bf16x8 b; } c; c.u = v; return c.b;
}

// fp8 e4m3 decode/accumulate via HW converts
__device__ __forceinline__ void acc_fp8x4(float4& s, unsigned v) {
    f32x2 lo = __builtin_amdgcn_cvt_pk_f32_fp8(v, false);
    f32x2 hi = __builtin_amdgcn_cvt_pk_f32_fp8(v, true);
    s.x += lo[0]; s.y += lo[1]; s.z += hi[0]; s.w += hi[1];
}

// ---------------- fused pre-pass: node degree hist + graph count + W1 pack ------
// blocks [0, EBLK)        : per-node degree histogram (direct global atomics,
//                           int4-vectorized dst reads; ~16 adds/address)
// blocks [EBLK, +391)     : per-graph node counts (batch histogram)
// blocks [EBLK+391, +256) : W1 -> bf16 fragment pack (+ zero sentinel g row)
__global__ __launch_bounds__(256) void pre_kernel(const int* __restrict__ ei,
                                                  int* __restrict__ degcur,
                                                  const int* __restrict__ batch,
                                                  float* __restrict__ cnt,
                                                  const float* __restrict__ W1,
                                                  ushort* __restrict__ w1f,
                                                  unsigned* __restrict__ gz) {
    __shared__ int h[NG];
    const int bid = blockIdx.x;
    const int t = threadIdx.x;
    if (bid < EBLK) {
        int idx = bid * 256 + t;
        if (idx < E4) {
            int4 d4 = ((const int4*)(ei + EE))[idx];
            atomicAdd(&degcur[d4.x], 1);
            atomicAdd(&degcur[d4.y], 1);
            atomicAdd(&degcur[d4.z], 1);
            atomicAdd(&degcur[d4.w], 1);
        }
    } else if (bid < EBLK + PRE_CNT_BLKS) {
        if (t < NG) h[t] = 0;
        __syncthreads();
        int i = (bid - EBLK) * 256 + t;
        if (i < NN) atomicAdd(&h[batch[i]], 1);
        __syncthreads();
        if (t < NG && h[t]) atomicAdd(&cnt[t], (float)h[t]);
    } else {
        int wb = bid - (EBLK + PRE_CNT_BLKS);
        int tt = wb * 256 + t;
        if (wb == 0 && t < 64) gz[t] = 0;   // sentinel g row NN = 0
        int k = tt >> 8, n = tt & 255;
        int kb = k >> 5, q = (k >> 3) & 3, j = k & 7;
        int nt = n >> 4, ln = (n & 15) + q * 16;
        w1f[(size_t)(((kb * 16 + nt) * 64) + ln) * 8 + j] = f2bf(W1[tt]);
    }
}

// ---------------- per-bucket padded-degree sums (LDS reduce) ----------------
__global__ __launch_bounds__(256) void bsum_kernel(const int* __restrict__ degcur,
                                                   int* __restrict__ bsum) {
    __shared__ int r[256];
    const int b = blockIdx.x;
    const int t = threadIdx.x;
    int node = b * 256 + t;
    int d = (node < NN) ? degcur[node] : 0;
    r[t] = (d + 7) & ~7;
    __syncthreads();
    for (int off = 128; off > 0; off >>= 1) {
        if (t < off) r[t] += r[t + off];
        __syncthreads();
    }
    if (t == 0) bsum[b] = r[0];
}

// ---------------- exclusive scan of 391 bucket sums ----------------
__global__ __launch_bounds__(512) void bucket_scan_kernel(const int* __restrict__ bsum,
                                                          int* __restrict__ bbase) {
    __shared__ int sc[512];
    const int t = threadIdx.x;
    int v = (t < NBK) ? bsum[t] : 0;
    sc[t] = v;
    __syncthreads();
    for (int off = 1; off < 512; off <<= 1) {
        int tmp = (t >= off) ? sc[t - off] : 0;
        __syncthreads();
        sc[t] += tmp;
        __syncthreads();
    }
    if (t < NBK) bbase[t] = sc[t] - v;
    if (t == NBK - 1) bbase[NBK] = sc[t];
}

// ---------------- per-node row starts, dinv, sentinels; cur init ----------------
// Exact padded-prefix layout: pstart = bbase[bucket] + local excl scan of pd.
// Everything is a multiple of 8 -> 32B-aligned regions for int4 index loads.
// cur aliases degcur (deg consumed here; scatter then bumps cur).
__global__ __launch_bounds__(256) void csrlite_kernel(int* __restrict__ degcur,
                                                      const int* __restrict__ bbase,
                                                      int* __restrict__ rowend,
                                                      float* __restrict__ dinv,
                                                      int* __restrict__ csrcol) {
    __shared__ int sc[256];
    const int b = blockIdx.x;
    const int t = threadIdx.x;
    int node = b * 256 + t;
    int d = (node < NN) ? degcur[node] : 0;
    int pd = (node < NN) ? ((d + 7) & ~7) : 0;
    sc[t] = pd;
    __syncthreads();
    for (int off = 1; off < 256; off <<= 1) {
        int tmp = (t >= off) ? sc[t - off] : 0;
        __syncthreads();
        sc[t] += tmp;
        __syncthreads();
    }
    if (node < NN) {
        int pstart = bbase[b] + sc[t] - pd;
        rowend[node] = pstart + pd;
        dinv[node] = rsqrtf((float)d + 1.0f);
        for (int j = d; j < pd; j++) csrcol[pstart + j] = NN;   // sentinels
        degcur[node] = pstart;                                  // becomes cur
    }
}

// ---------------- direct scatter: csrcol[cur[dst]++] = src ----------------
__global__ __launch_bounds__(256) void scatter_kernel(const int* __restrict__ ei,
                                                      int* __restrict__ cur,
                                                      int* __restrict__ csrcol) {
    int idx = blockIdx.x * 256 + threadIdx.x;
    if (idx >= E4) return;
    int4 s4 = ((const int4*)ei)[idx];
    int4 d4 = ((const int4*)(ei + EE))[idx];
    int p0 = atomicAdd(&cur[d4.x], 1); csrcol[p0] = s4.x;
    int p1 = atomicAdd(&cur[d4.y], 1); csrcol[p1] = s4.y;
    int p2 = atomicAdd(&cur[d4.z], 1); csrcol[p2] = s4.z;
    int p3 = atomicAdd(&cur[d4.w], 1); csrcol[p3] = s4.w;
}

// ---------------- g = fp8((x @ W1) * dinv[row]) — MFMA, LDS-free ----------------
// B-fragments batched into 16 NAMED uint4 registers per K-step so all 20 VMEM
// loads issue before one wait; launch_bounds(256,2) -> 256-VGPR cap.
// Epilogue stores CONTIGUOUS 16B per lane per row (transpose channel perm).
__global__ __launch_bounds__(256, 2) void gemm_mfma_kernel(const float* __restrict__ x,
                                                           const ushort* __restrict__ w1f,
                                                           const float* __restrict__ dinv,
                                                           uchar* __restrict__ g) {
    const int lane = threadIdx.x & 63;
    const int wid = threadIdx.x >> 6;
    const int wave = blockIdx.x * 4 + wid;
    const int r0 = wave * 32;
    if (r0 >= NN) return;
    const int mrow = lane & 15;
    const int q = lane >> 4;

    f32x4 acc[2][16];
    #pragma unroll
    for (int mt = 0; mt < 2; mt++)
        #pragma unroll
        for (int nt = 0; nt < 16; nt++)
            acc[mt][nt] = (f32x4){0.f, 0.f, 0.f, 0.f};

    const float* xp0 = x + (size_t)(r0 + mrow) * C + q * 8;
    const float* xp1 = xp0 + (size_t)16 * C;
    const ushort* bp = w1f + (size_t)lane * 8;

    #pragma unroll 1
    for (int kb = 0; kb < 8; kb++) {
        const int ko = kb * 32;
        float4 a0lo = *(const float4*)(xp0 + ko);
        float4 a0hi = *(const float4*)(xp0 + ko + 4);
        float4 a1lo = *(const float4*)(xp1 + ko);
        float4 a1hi = *(const float4*)(xp1 + ko + 4);
        uint4 bbv[16];
        const ushort* bkb = bp + (size_t)kb * 16 * 512;
        #pragma unroll
        for (int nt = 0; nt < 16; nt++)
            bbv[nt] = *(const uint4*)(bkb + (size_t)nt * 512);

        bf16x8 a0, a1;
        a0[0] = (__bf16)a0lo.x; a0[1] = (__bf16)a0lo.y;
        a0[2] = (__bf16)a0lo.z; a0[3] = (__bf16)a0lo.w;
        a0[4] = (__bf16)a0hi.x; a0[5] = (__bf16)a0hi.y;
        a0[6] = (__bf16)a0hi.z; a0[7] = (__bf16)a0hi.w;
        a1[0] = (__bf16)a1lo.x; a1[1] = (__bf16)a1lo.y;
        a1[2] = (__bf16)a1lo.z; a1[3] = (__bf16)a1lo.w;
        a1[4] = (__bf16)a1hi.x; a1[5] = (__bf16)a1hi.y;
        a1[6] = (__bf16)a1hi.z; a1[7] = (__bf16)a1hi.w;

        #pragma unroll
        for (int nt = 0; nt < 16; nt++) {
            bf16x8 bb = as_bf16x8(bbv[nt]);
            acc[0][nt] = __builtin_amdgcn_mfma_f32_16x16x32_bf16(a0, bb, acc[0][nt], 0, 0, 0);
            acc[1][nt] = __builtin_amdgcn_mfma_f32_16x16x32_bf16(a1, bb, acc[1][nt], 0, 0, 0);
        }
    }

    #pragma unroll
    for (int mt = 0; mt < 2; mt++) {
        #pragma unroll
        for (int r = 0; r < 4; r++) {
            int row = r0 + mt * 16 + q * 4 + r;
            float dv = dinv[row];
            uint4 dw;
            unsigned t0, t1, t2, t3;
            t0 = __builtin_amdgcn_cvt_pk_fp8_f32(acc[mt][0][r] * dv,  acc[mt][1][r] * dv,  0,  false);
            dw.x = __builtin_amdgcn_cvt_pk_fp8_f32(acc[mt][2][r] * dv,  acc[mt][3][r] * dv,  t0, true);
            t1 = __builtin_amdgcn_cvt_pk_fp8_f32(acc[mt][4][r] * dv,  acc[mt][5][r] * dv,  0,  false);
            dw.y = __builtin_amdgcn_cvt_pk_fp8_f32(acc[mt][6][r] * dv,  acc[mt][7][r] * dv,  t1, true);
            t2 = __builtin_amdgcn_cvt_pk_fp8_f32(acc[mt][8][r] * dv,  acc[mt][9][r] * dv,  0,  false);
            dw.z = __builtin_amdgcn_cvt_pk_fp8_f32(acc[mt][10][r] * dv, acc[mt][11][r] * dv, t2, true);
            t3 = __builtin_amdgcn_cvt_pk_fp8_f32(acc[mt][12][r] * dv, acc[mt][13][r] * dv, 0,  false);
            dw.w = __builtin_amdgcn_cvt_pk_fp8_f32(acc[mt][14][r] * dv, acc[mt][15][r] * dv, t3, true);
            *(uint4*)(g + (size_t)row * C + mrow * 16) = dw;
        }
    }
}

// ---------------- aggregate + relu + fused mean-pool (fp8, padded lists) --------
// R1-proven structure: full-row gather (64 lanes x 4B = 256B/record), separate
// self-loop load, int4 index loads (exact 32B-aligned regions). Launched as
// FOUR quarter dispatches (~33us each) so any prep kernel >33us surfaces in
// the profiler's top-5. Bias read through inverse channel permutation.
__global__ __launch_bounds__(256) void agg_pool_kernel(const unsigned* __restrict__ g32,
                                                       const int* __restrict__ rowend,
                                                       const int* __restrict__ csrcol,
                                                       const int* __restrict__ bbase,
                                                       const float* __restrict__ dinv,
                                                       const float* __restrict__ b1,
                                                       const int* __restrict__ batch,
                                                       float* __restrict__ sums,
                                                       const int blk0) {
    const int lane = threadIdx.x & 63;
    const int wid = threadIdx.x >> 6;
    const int c4 = lane * 4;
    const int nodeA = (blockIdx.x + blk0) * NODES_PER_BLOCK + wid * NODES_PER_GROUP;
    float4 bv;
    bv.x = b1[chan_logical(c4 + 0)];
    bv.y = b1[chan_logical(c4 + 1)];
    bv.z = b1[chan_logical(c4 + 2)];
    bv.w = b1[chan_logical(c4 + 3)];
    const unsigned* gp = g32 + lane;

    int rprev;
    if ((nodeA & 255) == 0) {
        rprev = bbase[nodeA >> BSH];        // exact bucket region start
    } else {
        rprev = rowend[nodeA - 1];
    }

    float4 pool = make_float4(0.f, 0.f, 0.f, 0.f);
    int curb = -1;
    #pragma unroll 1
    for (int i = nodeA; i < nodeA + NODES_PER_GROUP; i++) {
        int r1 = rowend[i];
        int r0 = rprev;
        rprev = r1;
        int bi = batch[i];
        if (bi != curb) {
            if (curb >= 0) {
                atomicAdd(&sums[curb * C + c4 + 0], pool.x);
                atomicAdd(&sums[curb * C + c4 + 1], pool.y);
                atomicAdd(&sums[curb * C + c4 + 2], pool.z);
                atomicAdd(&sums[curb * C + c4 + 3], pool.w);
            }
            curb = bi;
            pool = make_float4(0.f, 0.f, 0.f, 0.f);
        }
        float4 s = make_float4(0.f, 0.f, 0.f, 0.f);
        acc_fp8x4(s, gp[(size_t)i * 64]);               // self-loop term
        #pragma unroll 1
        for (int e = r0; e < r1; e += 8) {
            int4 iv0 = *(const int4*)(csrcol + e);       // 16B-aligned (e % 8 == 0)
            int4 iv1 = *(const int4*)(csrcol + e + 4);
            unsigned v0 = gp[(size_t)iv0.x * 64];
            unsigned v1 = gp[(size_t)iv0.y * 64];
            unsigned v2 = gp[(size_t)iv0.z * 64];
            unsigned v3 = gp[(size_t)iv0.w * 64];
            unsigned v4 = gp[(size_t)iv1.x * 64];
            unsigned v5 = gp[(size_t)iv1.y * 64];
            unsigned v6 = gp[(size_t)iv1.z * 64];
            unsigned v7 = gp[(size_t)iv1.w * 64];
            acc_fp8x4(s, v0); acc_fp8x4(s, v1); acc_fp8x4(s, v2); acc_fp8x4(s, v3);
            acc_fp8x4(s, v4); acc_fp8x4(s, v5); acc_fp8x4(s, v6); acc_fp8x4(s, v7);
        }
        float dv = dinv[i];
        pool.x += fmaxf(fmaf(dv, s.x, bv.x), 0.f);
        pool.y += fmaxf(fmaf(dv, s.y, bv.y), 0.f);
        pool.z += fmaxf(fmaf(dv, s.z, bv.z), 0.f);
        pool.w += fmaxf(fmaf(dv, s.w, bv.w), 0.f);
    }
    if (curb >= 0) {
        atomicAdd(&sums[curb * C + c4 + 0], pool.x);
        atomicAdd(&sums[curb * C + c4 + 1], pool.y);
        atomicAdd(&sums[curb * C + c4 + 2], pool.z);
        atomicAdd(&sums[curb * C + c4 + 3], pool.w);
    }
}

// ---------------- pooled = sums/cnt; out = pooled @ W2 + b2 ----------------
// sums/pooled in PHYSICAL (permuted) channel order; W2 indexed via inverse map.
__global__ __launch_bounds__(256) void final_kernel(const float* __restrict__ sums,
                                                    const float* __restrict__ cnt,
                                                    const float* __restrict__ W2,
                                                    const float* __restrict__ b2,
                                                    float* __restrict__ out) {
    __shared__ float p[C];
    int gi = blockIdx.x;
    float cdiv = fmaxf(cnt[gi], 1.0f);
    p[threadIdx.x] = sums[gi * C + threadIdx.x] / cdiv;
    __syncthreads();
    if (threadIdx.x < OUTC) {
        float acc = b2[threadIdx.x];
        for (int k = 0; k < C; k++)
            acc += p[k] * W2[chan_logical(k) * OUTC + threadIdx.x];
        out[gi * OUTC + threadIdx.x] = acc;
    }
}

extern "C" void kernel_launch(void* const* d_in, const int* in_sizes, int n_in,
                              void* d_out, int out_size, void* d_ws, size_t ws_size,
                              hipStream_t stream) {
    const float* x     = (const float*)d_in[0];
    const int*   ei    = (const int*)d_in[1];
    const int*   batch = (const int*)d_in[2];
    const float* W1    = (const float*)d_in[3];
    const float* b1    = (const float*)d_in[4];
    const float* W2    = (const float*)d_in[5];
    const float* b2    = (const float*)d_in[6];
    float* out = (float*)d_out;

    char* w = (char*)d_ws;
    size_t off = 0;
    auto carve = [&](size_t bytes) {
        void* p = w + off;
        off = (off + bytes + 255) & ~(size_t)255;
        return p;
    };
    uchar*    g        = (uchar*)   carve((size_t)(NN + 1) * C);  // fp8 + sentinel row
    int*      rowend   = (int*)     carve((size_t)NN * 4);
    float*    dinv     = (float*)   carve((size_t)NN * 4);
    int*      csrcol   = (int*)     carve((size_t)(EE + 8 * NN + 64) * 4);
    int*      bsum     = (int*)     carve((size_t)NBK * 4);
    int*      bbase    = (int*)     carve((size_t)(NBK + 1) * 4);
    ushort*   w1f      = (ushort*)  carve((size_t)C * C * 2);
    // contiguous zero-init region:
    int*      degcur   = (int*)     carve((size_t)NN * 4);
    float*    sums     = (float*)   carve((size_t)NG * C * 4);
    float*    cnt      = (float*)   carve((size_t)NG * 4);
    size_t zero_bytes = (size_t)((char*)cnt + (size_t)NG * 4 - (char*)degcur);

    hipMemsetAsync(degcur, 0, zero_bytes, stream);

    pre_kernel<<<EBLK + PRE_CNT_BLKS + PRE_W1_BLKS, 256, 0, stream>>>(
        ei, degcur, batch, cnt, W1, w1f, (unsigned*)(g + (size_t)NN * C));
    bsum_kernel<<<NBK, 256, 0, stream>>>(degcur, bsum);
    bucket_scan_kernel<<<1, 512, 0, stream>>>(bsum, bbase);
    csrlite_kernel<<<NBK, 256, 0, stream>>>(degcur, bbase, rowend, dinv, csrcol);
    scatter_kernel<<<EBLK, 256, 0, stream>>>(ei, degcur, csrcol);
    gemm_mfma_kernel<<<(NN / 32 + 3) / 4, 256, 0, stream>>>(x, w1f, dinv, g);
    agg_pool_kernel<<<AGG_Q, 256, 0, stream>>>(
        (const unsigned*)g, rowend, csrcol, bbase, dinv, b1, batch, sums, 0);
    agg_pool_kernel<<<AGG_Q, 256, 0, stream>>>(
        (const unsigned*)g, rowend, csrcol, bbase, dinv, b1, batch, sums, AGG_Q);
    agg_pool_kernel<<<AGG_Q, 256, 0, stream>>>(
        (const unsigned*)g, rowend, csrcol, bbase, dinv, b1, batch, sums, 2 * AGG_Q);
    agg_pool_kernel<<<AGG_BLOCKS - 3 * AGG_Q, 256, 0, stream>>>(
        (const unsigned*)g, rowend, csrcol, bbase, dinv, b1, batch, sums, 3 * AGG_Q);
    final_kernel<<<NG, 256, 0, stream>>>(sums, cnt, W2, b2, out);
}

// Round 10
// 458.959 us; speedup vs baseline: 1.3302x; 1.3302x over previous
//
#include <hip/hip_runtime.h>

#define NN 100000
#define EE 1600000
#define C 256
#define OUTC 10
#define NG 64

#define BSH 7              // bucket = dst >> 7 (128-node buckets)
#define NBK 782            // ceil(NN/128)
#define CHUNK 4096         // edges per chunk
#define NCHUNK 391         // ceil(EE/CHUNK)
#define CI4 1024           // int4 slots per chunk
#define E4 (EE / 4)        // 400000 int4 slots total
#define PADSLACK 1024      // per-bucket csrcol slack: 128*7 pad + 7 align < 1024

// agg_pool decomposition: 4 waves/block, each wave owns NODES_PER_GROUP nodes
#define NODES_PER_GROUP 8
#define NODES_PER_BLOCK 32      // 100000 = 32 * 3125 exactly
#define AGG_BLOCKS 3125
#define AGG_Q 782               // quarter split: 782,782,782,779

#define PRE_CNT_BLKS 391        // count blocks
#define PRE_W1_BLKS 256         // w1pack blocks

typedef __bf16 bf16x8 __attribute__((ext_vector_type(8)));
typedef float f32x4 __attribute__((ext_vector_type(4)));
typedef float f32x2 __attribute__((ext_vector_type(2)));

// channel permutation: PHYSICAL byte position p in a g row holds LOGICAL
// channel c = ((p&15)<<4) | (p>>4)  (transpose involution).
__device__ __forceinline__ int chan_logical(int p) {
    return ((p & 15) << 4) | (p >> 4);
}

// ---------------- bf16 helpers (RNE) ----------------
__device__ __forceinline__ ushort f2bf(float f) {
    unsigned u = __float_as_uint(f);
    return (ushort)((u + 0x7fffu + ((u >> 16) & 1u)) >> 16);
}
__device__ __forceinline__ bf16x8 as_bf16x8(uint4 v) {
    union { uint4 u; bf16x8 b; } c; c.u = v; return c.b;
}

// fp8 e4m3 decode/accumulate via HW converts
__device__ __forceinline__ void acc_fp8x4(float4& s, unsigned v) {
    f32x2 lo = __builtin_amdgcn_cvt_pk_f32_fp8(v, false);
    f32x2 hi = __builtin_amdgcn_cvt_pk_f32_fp8(v, true);
    s.x += lo[0]; s.y += lo[1]; s.z += hi[0]; s.w += hi[1];
}

// ---------------- fused pre-pass: per-chunk bucket hist + count + W1 pack -------
// blocks [0, NCHUNK)       : LDS histogram of chunk's dst>>7, written as a
//                            CONTIGUOUS row chunkhist[c][0..NBK) (no atomics,
//                            no zero-init needed - every entry written)
// blocks [NCHUNK, +391)    : per-graph node counts (batch histogram)
// blocks [NCHUNK+391,+256) : W1 -> bf16 fragment pack (+ zero sentinel g row)
__global__ __launch_bounds__(256) void pre_kernel(const int* __restrict__ ei,
                                                  int* __restrict__ chunkhist,
                                                  const int* __restrict__ batch,
                                                  float* __restrict__ cnt,
                                                  const float* __restrict__ W1,
                                                  ushort* __restrict__ w1f,
                                                  unsigned* __restrict__ gz) {
    __shared__ int h[NBK];
    const int bid = blockIdx.x;
    const int t = threadIdx.x;
    if (bid < NCHUNK) {
        for (int i = t; i < NBK; i += 256) h[i] = 0;
        __syncthreads();
        const int base4 = bid * CI4;
        const int end4 = min(base4 + CI4, E4);
        for (int i = base4 + t; i < end4; i += 256) {
            int4 d4 = ((const int4*)(ei + EE))[i];
            atomicAdd(&h[d4.x >> BSH], 1);
            atomicAdd(&h[d4.y >> BSH], 1);
            atomicAdd(&h[d4.z >> BSH], 1);
            atomicAdd(&h[d4.w >> BSH], 1);
        }
        __syncthreads();
        for (int i = t; i < NBK; i += 256)
            chunkhist[bid * NBK + i] = h[i];
    } else if (bid < NCHUNK + PRE_CNT_BLKS) {
        if (t < NG) h[t] = 0;
        __syncthreads();
        int i = (bid - NCHUNK) * 256 + t;
        if (i < NN) atomicAdd(&h[batch[i]], 1);
        __syncthreads();
        if (t < NG && h[t]) atomicAdd(&cnt[t], (float)h[t]);
    } else {
        int wb = bid - (NCHUNK + PRE_CNT_BLKS);
        int tt = wb * 256 + t;
        if (wb == 0 && t < 64) gz[t] = 0;   // sentinel g row NN = 0
        int k = tt >> 8, n = tt & 255;
        int kb = k >> 5, q = (k >> 3) & 3, j = k & 7;
        int nt = n >> 4, ln = (n & 15) + q * 16;
        w1f[(size_t)(((kb * 16 + nt) * 64) + ln) * 8 + j] = f2bf(W1[tt]);
    }
}

// ---------------- per-bucket scan over chunks: excl offsets + bucket totals -----
// block b: load column chunkhist[c][b] (c=0..NCHUNK-1), exclusive LDS scan,
// write back in place; total -> bsum[b].
__global__ __launch_bounds__(512) void rowscan_kernel(int* __restrict__ chunkhist,
                                                      int* __restrict__ bsum) {
    __shared__ int sc[512];
    const int b = blockIdx.x;
    const int t = threadIdx.x;
    int v = (t < NCHUNK) ? chunkhist[t * NBK + b] : 0;
    sc[t] = v;
    __syncthreads();
    for (int off = 1; off < 512; off <<= 1) {
        int tmp = (t >= off) ? sc[t - off] : 0;
        __syncthreads();
        sc[t] += tmp;
        __syncthreads();
    }
    if (t < NCHUNK) chunkhist[t * NBK + b] = sc[t] - v;
    if (t == 511) bsum[b] = sc[511];
}

// ---------------- exclusive scan of 782 bucket totals ----------------
__global__ __launch_bounds__(1024) void bucket_scan_kernel(const int* __restrict__ bsum,
                                                           int* __restrict__ bbase) {
    __shared__ int sc[1024];
    const int t = threadIdx.x;
    int v = (t < NBK) ? bsum[t] : 0;
    sc[t] = v;
    __syncthreads();
    for (int off = 1; off < 1024; off <<= 1) {
        int tmp = (t >= off) ? sc[t - off] : 0;
        __syncthreads();
        sc[t] += tmp;
        __syncthreads();
    }
    if (t < NBK) bbase[t] = sc[t] - v;
    if (t == NBK - 1) bbase[NBK] = sc[t];
}

// ---------------- atomic-free scatter into bucket-major records ----------------
// block c seeds LDS cursors from bbase[b] + chunkhist[c][b] (precomputed
// exclusive offsets) - no global atomics, no second histogram pass.
// record = (dst & 127) << 17 | src
__global__ __launch_bounds__(256) void bucket_scatter_kernel(const int* __restrict__ ei,
                                                             const int* __restrict__ chunkhist,
                                                             const int* __restrict__ bbase,
                                                             unsigned* __restrict__ bmaj) {
    __shared__ int cur[NBK];
    const int c = blockIdx.x;
    const int t = threadIdx.x;
    for (int b = t; b < NBK; b += 256)
        cur[b] = bbase[b] + chunkhist[c * NBK + b];
    __syncthreads();
    const int base4 = c * CI4;
    const int end4 = min(base4 + CI4, E4);
    for (int i = base4 + t; i < end4; i += 256) {
        int4 s4 = ((const int4*)ei)[i];
        int4 d4 = ((const int4*)(ei + EE))[i];
        int p0 = atomicAdd(&cur[d4.x >> BSH], 1);
        bmaj[p0] = (unsigned)s4.x | ((unsigned)(d4.x & 127) << 17);
        int p1 = atomicAdd(&cur[d4.y >> BSH], 1);
        bmaj[p1] = (unsigned)s4.y | ((unsigned)(d4.y & 127) << 17);
        int p2 = atomicAdd(&cur[d4.z >> BSH], 1);
        bmaj[p2] = (unsigned)s4.z | ((unsigned)(d4.z & 127) << 17);
        int p3 = atomicAdd(&cur[d4.w >> BSH], 1);
        bmaj[p3] = (unsigned)s4.w | ((unsigned)(d4.w & 127) << 17);
    }
}

// ---------------- per-bucket: degree, PADDED rowend, dinv, dense csrcol ----------
// 128-node buckets. Node lists = edges padded to mult of 8 with sentinel NN
// (zero g row); self-loop handled in agg directly. Region b starts at
// align8(bbase[b]) + b*PADSLACK (16B-aligned int4 loads).
__global__ __launch_bounds__(256) void bucket_csr_kernel(const unsigned* __restrict__ bmaj,
                                                         const int* __restrict__ bbase,
                                                         int* __restrict__ rowend,
                                                         float* __restrict__ dinv,
                                                         int* __restrict__ csrcol) {
    __shared__ int h[128];
    __shared__ int sc[128];
    __shared__ int cur[128];
    const int b = blockIdx.x;
    const int t = threadIdx.x;
    const int e0 = bbase[b], e1 = bbase[b + 1];
    const int region0 = ((e0 + 7) & ~7) + b * PADSLACK;   // 8-int aligned
    if (t < 128) h[t] = 0;
    __syncthreads();
    for (int e = e0 + t; e < e1; e += 256)
        atomicAdd(&h[bmaj[e] >> 17], 1);
    __syncthreads();
    int deg = 0, pd = 0, node = 0;
    if (t < 128) {
        deg = h[t];
        node = b * 128 + t;
        pd = (node < NN) ? ((deg + 7) & ~7) : 0;
        sc[t] = pd;
    }
    __syncthreads();
    for (int off = 1; off < 128; off <<= 1) {
        int tmp = (t >= off && t < 128) ? sc[t - off] : 0;
        __syncthreads();
        if (t < 128) sc[t] += tmp;
        __syncthreads();
    }
    if (t < 128) {
        int pstart = region0 + sc[t] - pd;
        if (node < NN) {
            rowend[node] = pstart + pd;        // PADDED end
            dinv[node] = rsqrtf((float)deg + 1.0f);
            for (int j = deg; j < pd; j++) csrcol[pstart + j] = NN;   // sentinels
        }
        cur[t] = pstart;
    }
    __syncthreads();
    for (int e = e0 + t; e < e1; e += 256) {
        unsigned v = bmaj[e];
        int p = atomicAdd(&cur[v >> 17], 1);
        csrcol[p] = (int)(v & 0x1FFFFu);
    }
}

// ---------------- g = fp8((x @ W1) * dinv[row]) — MFMA, LDS-free ----------------
// B-fragments batched into 16 NAMED uint4 registers per K-step so all 20 VMEM
// loads issue before one wait; launch_bounds(256,2) -> 256-VGPR cap.
// Epilogue stores CONTIGUOUS 16B per lane per row (transpose channel perm).
__global__ __launch_bounds__(256, 2) void gemm_mfma_kernel(const float* __restrict__ x,
                                                           const ushort* __restrict__ w1f,
                                                           const float* __restrict__ dinv,
                                                           uchar* __restrict__ g) {
    const int lane = threadIdx.x & 63;
    const int wid = threadIdx.x >> 6;
    const int wave = blockIdx.x * 4 + wid;
    const int r0 = wave * 32;
    if (r0 >= NN) return;
    const int mrow = lane & 15;
    const int q = lane >> 4;

    f32x4 acc[2][16];
    #pragma unroll
    for (int mt = 0; mt < 2; mt++)
        #pragma unroll
        for (int nt = 0; nt < 16; nt++)
            acc[mt][nt] = (f32x4){0.f, 0.f, 0.f, 0.f};

    const float* xp0 = x + (size_t)(r0 + mrow) * C + q * 8;
    const float* xp1 = xp0 + (size_t)16 * C;
    const ushort* bp = w1f + (size_t)lane * 8;

    #pragma unroll 1
    for (int kb = 0; kb < 8; kb++) {
        const int ko = kb * 32;
        float4 a0lo = *(const float4*)(xp0 + ko);
        float4 a0hi = *(const float4*)(xp0 + ko + 4);
        float4 a1lo = *(const float4*)(xp1 + ko);
        float4 a1hi = *(const float4*)(xp1 + ko + 4);
        uint4 bbv[16];
        const ushort* bkb = bp + (size_t)kb * 16 * 512;
        #pragma unroll
        for (int nt = 0; nt < 16; nt++)
            bbv[nt] = *(const uint4*)(bkb + (size_t)nt * 512);

        bf16x8 a0, a1;
        a0[0] = (__bf16)a0lo.x; a0[1] = (__bf16)a0lo.y;
        a0[2] = (__bf16)a0lo.z; a0[3] = (__bf16)a0lo.w;
        a0[4] = (__bf16)a0hi.x; a0[5] = (__bf16)a0hi.y;
        a0[6] = (__bf16)a0hi.z; a0[7] = (__bf16)a0hi.w;
        a1[0] = (__bf16)a1lo.x; a1[1] = (__bf16)a1lo.y;
        a1[2] = (__bf16)a1lo.z; a1[3] = (__bf16)a1lo.w;
        a1[4] = (__bf16)a1hi.x; a1[5] = (__bf16)a1hi.y;
        a1[6] = (__bf16)a1hi.z; a1[7] = (__bf16)a1hi.w;

        #pragma unroll
        for (int nt = 0; nt < 16; nt++) {
            bf16x8 bb = as_bf16x8(bbv[nt]);
            acc[0][nt] = __builtin_amdgcn_mfma_f32_16x16x32_bf16(a0, bb, acc[0][nt], 0, 0, 0);
            acc[1][nt] = __builtin_amdgcn_mfma_f32_16x16x32_bf16(a1, bb, acc[1][nt], 0, 0, 0);
        }
    }

    #pragma unroll
    for (int mt = 0; mt < 2; mt++) {
        #pragma unroll
        for (int r = 0; r < 4; r++) {
            int row = r0 + mt * 16 + q * 4 + r;
            float dv = dinv[row];
            uint4 dw;
            unsigned t0, t1, t2, t3;
            t0 = __builtin_amdgcn_cvt_pk_fp8_f32(acc[mt][0][r] * dv,  acc[mt][1][r] * dv,  0,  false);
            dw.x = __builtin_amdgcn_cvt_pk_fp8_f32(acc[mt][2][r] * dv,  acc[mt][3][r] * dv,  t0, true);
            t1 = __builtin_amdgcn_cvt_pk_fp8_f32(acc[mt][4][r] * dv,  acc[mt][5][r] * dv,  0,  false);
            dw.y = __builtin_amdgcn_cvt_pk_fp8_f32(acc[mt][6][r] * dv,  acc[mt][7][r] * dv,  t1, true);
            t2 = __builtin_amdgcn_cvt_pk_fp8_f32(acc[mt][8][r] * dv,  acc[mt][9][r] * dv,  0,  false);
            dw.z = __builtin_amdgcn_cvt_pk_fp8_f32(acc[mt][10][r] * dv, acc[mt][11][r] * dv, t2, true);
            t3 = __builtin_amdgcn_cvt_pk_fp8_f32(acc[mt][12][r] * dv, acc[mt][13][r] * dv, 0,  false);
            dw.w = __builtin_amdgcn_cvt_pk_fp8_f32(acc[mt][14][r] * dv, acc[mt][15][r] * dv, t3, true);
            *(uint4*)(g + (size_t)row * C + mrow * 16) = dw;
        }
    }
}

// ---------------- aggregate + relu + fused mean-pool (fp8, padded lists) --------
// R1-proven structure: full-row gather (64 lanes x 4B = 256B/record), separate
// self-loop load, int4 index loads. FOUR quarter dispatches (~33us top-5
// visibility floor). Bias read through inverse channel permutation.
__global__ __launch_bounds__(256) void agg_pool_kernel(const unsigned* __restrict__ g32,
                                                       const int* __restrict__ rowend,
                                                       const int* __restrict__ csrcol,
                                                       const int* __restrict__ bbase,
                                                       const float* __restrict__ dinv,
                                                       const float* __restrict__ b1,
                                                       const int* __restrict__ batch,
                                                       float* __restrict__ sums,
                                                       const int blk0) {
    const int lane = threadIdx.x & 63;
    const int wid = threadIdx.x >> 6;
    const int c4 = lane * 4;
    const int nodeA = (blockIdx.x + blk0) * NODES_PER_BLOCK + wid * NODES_PER_GROUP;
    float4 bv;
    bv.x = b1[chan_logical(c4 + 0)];
    bv.y = b1[chan_logical(c4 + 1)];
    bv.z = b1[chan_logical(c4 + 2)];
    bv.w = b1[chan_logical(c4 + 3)];
    const unsigned* gp = g32 + lane;

    int rprev;
    if ((nodeA & 127) == 0) {
        int b = nodeA >> BSH;
        rprev = ((bbase[b] + 7) & ~7) + b * PADSLACK;   // aligned bucket region start
    } else {
        rprev = rowend[nodeA - 1];
    }

    float4 pool = make_float4(0.f, 0.f, 0.f, 0.f);
    int curb = -1;
    #pragma unroll 1
    for (int i = nodeA; i < nodeA + NODES_PER_GROUP; i++) {
        int r1 = rowend[i];
        int r0 = rprev;
        rprev = r1;
        int bi = batch[i];
        if (bi != curb) {
            if (curb >= 0) {
                atomicAdd(&sums[curb * C + c4 + 0], pool.x);
                atomicAdd(&sums[curb * C + c4 + 1], pool.y);
                atomicAdd(&sums[curb * C + c4 + 2], pool.z);
                atomicAdd(&sums[curb * C + c4 + 3], pool.w);
            }
            curb = bi;
            pool = make_float4(0.f, 0.f, 0.f, 0.f);
        }
        float4 s = make_float4(0.f, 0.f, 0.f, 0.f);
        acc_fp8x4(s, gp[(size_t)i * 64]);               // self-loop term
        #pragma unroll 1
        for (int e = r0; e < r1; e += 8) {
            int4 iv0 = *(const int4*)(csrcol + e);       // 16B-aligned (e % 8 == 0)
            int4 iv1 = *(const int4*)(csrcol + e + 4);
            unsigned v0 = gp[(size_t)iv0.x * 64];
            unsigned v1 = gp[(size_t)iv0.y * 64];
            unsigned v2 = gp[(size_t)iv0.z * 64];
            unsigned v3 = gp[(size_t)iv0.w * 64];
            unsigned v4 = gp[(size_t)iv1.x * 64];
            unsigned v5 = gp[(size_t)iv1.y * 64];
            unsigned v6 = gp[(size_t)iv1.z * 64];
            unsigned v7 = gp[(size_t)iv1.w * 64];
            acc_fp8x4(s, v0); acc_fp8x4(s, v1); acc_fp8x4(s, v2); acc_fp8x4(s, v3);
            acc_fp8x4(s, v4); acc_fp8x4(s, v5); acc_fp8x4(s, v6); acc_fp8x4(s, v7);
        }
        float dv = dinv[i];
        pool.x += fmaxf(fmaf(dv, s.x, bv.x), 0.f);
        pool.y += fmaxf(fmaf(dv, s.y, bv.y), 0.f);
        pool.z += fmaxf(fmaf(dv, s.z, bv.z), 0.f);
        pool.w += fmaxf(fmaf(dv, s.w, bv.w), 0.f);
    }
    if (curb >= 0) {
        atomicAdd(&sums[curb * C + c4 + 0], pool.x);
        atomicAdd(&sums[curb * C + c4 + 1], pool.y);
        atomicAdd(&sums[curb * C + c4 + 2], pool.z);
        atomicAdd(&sums[curb * C + c4 + 3], pool.w);
    }
}

// ---------------- pooled = sums/cnt; out = pooled @ W2 + b2 ----------------
// sums/pooled in PHYSICAL (permuted) channel order; W2 indexed via inverse map.
__global__ __launch_bounds__(256) void final_kernel(const float* __restrict__ sums,
                                                    const float* __restrict__ cnt,
                                                    const float* __restrict__ W2,
                                                    const float* __restrict__ b2,
                                                    float* __restrict__ out) {
    __shared__ float p[C];
    int gi = blockIdx.x;
    float cdiv = fmaxf(cnt[gi], 1.0f);
    p[threadIdx.x] = sums[gi * C + threadIdx.x] / cdiv;
    __syncthreads();
    if (threadIdx.x < OUTC) {
        float acc = b2[threadIdx.x];
        for (int k = 0; k < C; k++)
            acc += p[k] * W2[chan_logical(k) * OUTC + threadIdx.x];
        out[gi * OUTC + threadIdx.x] = acc;
    }
}

extern "C" void kernel_launch(void* const* d_in, const int* in_sizes, int n_in,
                              void* d_out, int out_size, void* d_ws, size_t ws_size,
                              hipStream_t stream) {
    const float* x     = (const float*)d_in[0];
    const int*   ei    = (const int*)d_in[1];
    const int*   batch = (const int*)d_in[2];
    const float* W1    = (const float*)d_in[3];
    const float* b1    = (const float*)d_in[4];
    const float* W2    = (const float*)d_in[5];
    const float* b2    = (const float*)d_in[6];
    float* out = (float*)d_out;

    char* w = (char*)d_ws;
    size_t off = 0;
    auto carve = [&](size_t bytes) {
        void* p = w + off;
        off = (off + bytes + 255) & ~(size_t)255;
        return p;
    };
    uchar*    g        = (uchar*)   carve((size_t)(NN + 1) * C);  // fp8 + sentinel row
    int*      rowend   = (int*)     carve((size_t)NN * 4);
    float*    dinv     = (float*)   carve((size_t)NN * 4);
    int*      csrcol   = (int*)     carve((size_t)(EE + (size_t)NBK * PADSLACK + 128) * 4);
    unsigned* bmaj     = (unsigned*)carve((size_t)EE * 4);
    int*      chunkhist= (int*)     carve((size_t)NCHUNK * NBK * 4);
    int*      bsum     = (int*)     carve((size_t)NBK * 4);
    int*      bbase    = (int*)     carve((size_t)(NBK + 1) * 4);
    ushort*   w1f      = (ushort*)  carve((size_t)C * C * 2);
    // contiguous zero-init region:
    float*    sums     = (float*)   carve((size_t)NG * C * 4);
    float*    cnt      = (float*)   carve((size_t)NG * 4);
    size_t zero_bytes = (size_t)((char*)cnt + (size_t)NG * 4 - (char*)sums);

    hipMemsetAsync(sums, 0, zero_bytes, stream);

    pre_kernel<<<NCHUNK + PRE_CNT_BLKS + PRE_W1_BLKS, 256, 0, stream>>>(
        ei, chunkhist, batch, cnt, W1, w1f, (unsigned*)(g + (size_t)NN * C));
    rowscan_kernel<<<NBK, 512, 0, stream>>>(chunkhist, bsum);
    bucket_scan_kernel<<<1, 1024, 0, stream>>>(bsum, bbase);
    bucket_scatter_kernel<<<NCHUNK, 256, 0, stream>>>(ei, chunkhist, bbase, bmaj);
    bucket_csr_kernel<<<NBK, 256, 0, stream>>>(bmaj, bbase, rowend, dinv, csrcol);
    gemm_mfma_kernel<<<(NN / 32 + 3) / 4, 256, 0, stream>>>(x, w1f, dinv, g);
    agg_pool_kernel<<<AGG_Q, 256, 0, stream>>>(
        (const unsigned*)g, rowend, csrcol, bbase, dinv, b1, batch, sums, 0);
    agg_pool_kernel<<<AGG_Q, 256, 0, stream>>>(
        (const unsigned*)g, rowend, csrcol, bbase, dinv, b1, batch, sums, AGG_Q);
    agg_pool_kernel<<<AGG_Q, 256, 0, stream>>>(
        (const unsigned*)g, rowend, csrcol, bbase, dinv, b1, batch, sums, 2 * AGG_Q);
    agg_pool_kernel<<<AGG_BLOCKS - 3 * AGG_Q, 256, 0, stream>>>(
        (const unsigned*)g, rowend, csrcol, bbase, dinv, b1, batch, sums, 3 * AGG_Q);
    final_kernel<<<NG, 256, 0, stream>>>(sums, cnt, W2, b2, out);
}